// Round 8
// baseline (213.685 us; speedup 1.0000x reference)
//
#include <hip/hip_runtime.h>
#include <math.h>

#define HH 160
#define WW 160
#define DD 160
#define VOL (HH*WW*DD)          // 4,096,000
#define KS 11
#define PAD 5
#define NBATCH 2
#define NTOT (NBATCH*VOL)

// fused tile geometry
#define WT 16                    // w outputs per block
#define DT 16                    // d outputs per block
#define HT 32                    // h outputs per block (delay-line walk)
#define WPN (WT + 2*PAD)         // 26 w rows incl. halo
#define NSTEP (HT + 2*PAD)       // 42
// LDS strides (words) — words-per-bank audited for the wide-op wave shapes
#define RS 74                    // raw row (r6-proven)
#define P01S 36                  // b128 base 4(wl+dp) -> 8 words/bank = minimum; 16B aligned
#define P4S 20                   // b64 bases {0,20,8,28,16,4,24,12} -> 4 words/bank = minimum
#define RAW_W (WPN*RS)           // 1924 words per raw buffer
#define P01_W (WPN*P01S)         // 936
#define P4_W  (WPN*P4S)          // 520

typedef float v2f __attribute__((ext_vector_type(2)));
typedef float v4f __attribute__((ext_vector_type(4)));

struct Wts { float w[KS]; };

__device__ __forceinline__ int mirror(int i, int n) {
    if (i < 0) i = -i;
    if (i >= n) i = 2*n - 2 - i;
    return i;
}

// tied VOP3P asm: in-place accumulate, no result-copy movs
__device__ __forceinline__ void pk_fma_acc(v2f& c, v2f a, v2f b) {
    asm("v_pk_fma_f32 %0, %1, %2, %0" : "+v"(c) : "v"(a), "v"(b));
}
__device__ __forceinline__ void pk_add_acc(v2f& c, v2f a) {
    asm("v_pk_add_f32 %0, %0, %1" : "+v"(c) : "v"(a));
}
__device__ __forceinline__ v2f pk_mul(v2f a, v2f b) {
    v2f d; asm("v_pk_mul_f32 %0, %1, %2" : "=v"(d) : "v"(a), "v"(b)); return d;
}

__global__ void init_out(float* out) {
    if (threadIdx.x == 0 && blockIdx.x == 0) out[0] = 1.0f;
}

// Fully fused 3D SSIM.
// Round-8 (r6 base + LDS-instruction cuts, VALU-neutral):
//  - phase2 d-pair: 128 threads x 2 outputs; taps via b128 (pl01/pl23) + b64
//    (pl4) -> LDS ops per output halved, ring stays packed (5 pk/slot/2outs).
//  - strides P01S=36/P4S=20: words-per-bank = data minimum for the wide ops.
//  - phase1 plane writes fused to 2x b128 + 1x b64 (balanced, 6->3 instrs).
//  - interior-h blocks skip mirror() (uniform branch).
__global__ __launch_bounds__(256) void fused(const float* __restrict__ src,
                                             const float* __restrict__ ref,
                                             float* __restrict__ out,
                                             Wts wts, float scale) {
    __shared__ __align__(16) float raw [2*RAW_W];   // (s,r) interleaved window
    __shared__ __align__(16) float pl01[2*P01_W];   // (mu1,mu2) pairs, d-paired
    __shared__ __align__(16) float pl23[2*P01_W];   // (m11,m22)
    __shared__ __align__(16) float pl4 [2*P4_W];    // (m12 d0, m12 d1) pairs

    const int bx  = blockIdx.x;
    const int dt_ = bx % (DD/DT);
    const int wt_ = (bx / (DD/DT)) % (WW/WT);
    const int ht_ = (bx / ((DD/DT)*(WW/WT))) % (HH/HT);
    const int b   = bx / ((DD/DT)*(WW/WT)*(HH/HT));
    const int d0 = dt_*DT, w0 = wt_*WT, h0 = ht_*HT;

    const int  dbase = (d0 == 0) ? 0 : ((d0 == DD-DT) ? DD-32 : d0-8);
    const bool dedge = (d0 == 0) || (d0 == DD-DT);
    const bool hedge = (ht_ == 0) || (ht_ == HH/HT - 1);

    const int tid = threadIdx.x;
    const float* __restrict__ sp = src + (size_t)b*VOL;
    const float* __restrict__ rp = ref + (size_t)b*VOL;

    // ---- stage identity: 208 threads, (row swp, quad sq) ----
    const bool sact = (tid < WPN*8);                 // 208: stage AND phase1
    const int  swp = tid >> 3, sq = tid & 7;
    const int  sgoff  = mirror(w0 - PAD + (sact ? swp : 0), WW)*DD + dbase + sq*4;
    const int  srawof = swp*RS + sq*8;

    // ---- phase1 identity: thread (p_wp, p_dlp) owns points d=2dlp, 2dlp+1 ----
    const int  p_wp  = tid >> 3;                     // 0..25
    const int  p_dlp = tid & 7;                      // 0..7
    const int  pA01  = p_wp*P01S + 4*p_dlp;          // 16B-aligned b128 slot
    const int  pA4   = p_wp*P4S  + 2*p_dlp;          // 8B-aligned b64 slot
    const int  p_rbase = p_wp*RS + 6 + 4*p_dlp;      // interior tap base

    int eoff[12];
    if (dedge) {
#pragma unroll
        for (int j = 0; j < 12; ++j)
            eoff[j] = 2*(mirror(d0 + 2*p_dlp - PAD + j, DD) - dbase);
    }

    // ---- phase2 identity: 128 threads, output pair (w0+wl, d0+2dp / 2dp+1) ----
    const bool p2act = (tid < 128);
    const int  wl = (tid >> 3) & 15;                 // 0..15
    const int  dp = tid & 7;                         // 0..7
    const int  q01b = wl*P01S + 4*dp;
    const int  q4b  = wl*P4S  + 2*dp;

    v2f wpk[KS];
#pragma unroll
    for (int k = 0; k < KS; ++k) { wpk[k].x = wts.w[k]; wpk[k].y = wts.w[k]; }

    // H delay-line ring: packed channel pairs, two outputs (A=d0, B=d1)
    v2f a01A[KS], a01B[KS], a23A[KS], a23B[KS], a4[KS];
#pragma unroll
    for (int s = 0; s < KS; ++s) {
        a01A[s] = (v2f)0.f; a01B[s] = (v2f)0.f;
        a23A[s] = (v2f)0.f; a23B[s] = (v2f)0.f; a4[s] = (v2f)0.f;
    }

    // ---- prologue: stage step 0 into raw half 0, prefetch step 1 ----
    v4f ra = (v4f)0.f, rb_ = (v4f)0.f;
    if (sact) {
        int hm0 = h0 - PAD;           if (hedge) hm0 = mirror(hm0, HH);
        const size_t o0 = (size_t)hm0*(WW*DD) + sgoff;
        ra  = *reinterpret_cast<const v4f*>(sp + o0);
        rb_ = *reinterpret_cast<const v4f*>(rp + o0);
        v2f p0, p1, p2, p3;
        p0.x=ra.x; p0.y=rb_.x;  p1.x=ra.y; p1.y=rb_.y;
        p2.x=ra.z; p2.y=rb_.z;  p3.x=ra.w; p3.y=rb_.w;
        *reinterpret_cast<v2f*>(&raw[srawof])     = p0;
        *reinterpret_cast<v2f*>(&raw[srawof + 2]) = p1;
        *reinterpret_cast<v2f*>(&raw[srawof + 4]) = p2;
        *reinterpret_cast<v2f*>(&raw[srawof + 6]) = p3;
        int hm1 = h0 - PAD + 1;       if (hedge) hm1 = mirror(hm1, HH);
        const size_t o1 = (size_t)hm1*(WW*DD) + sgoff;
        ra  = *reinterpret_cast<const v4f*>(sp + o1);
        rb_ = *reinterpret_cast<const v4f*>(rp + o1);
    }
    __syncthreads();

    float ssum = 0.f;
    int rawRd = 0, rawWr = RAW_W, po01 = 0, po4 = 0;

#pragma unroll 1
    for (int tb = 0; tb < 44; tb += 11) {
#pragma unroll
        for (int ts = 0; ts < 11; ++ts) {
            const int t = tb + ts;
            if (t < NSTEP) {                     // block-uniform
                if (sact) {
                    // ---- A: stage step t+1 (prefetched regs) -> raw[rawWr] ----
                    v2f p0, p1, p2, p3;
                    p0.x=ra.x; p0.y=rb_.x;  p1.x=ra.y; p1.y=rb_.y;
                    p2.x=ra.z; p2.y=rb_.z;  p3.x=ra.w; p3.y=rb_.w;
                    *reinterpret_cast<v2f*>(&raw[rawWr + srawof])     = p0;
                    *reinterpret_cast<v2f*>(&raw[rawWr + srawof + 2]) = p1;
                    *reinterpret_cast<v2f*>(&raw[rawWr + srawof + 4]) = p2;
                    *reinterpret_cast<v2f*>(&raw[rawWr + srawof + 6]) = p3;
                    // ---- B: re-issue prefetch for step t+2 (overrun stays
                    //      in-bounds: interior blocks h<=h0+38, edge mirrored) ----
                    int hn = h0 - PAD + t + 2;  if (hedge) hn = mirror(hn, HH);
                    const size_t on = (size_t)hn*(WW*DD) + sgoff;
                    ra  = *reinterpret_cast<const v4f*>(sp + on);
                    rb_ = *reinterpret_cast<const v4f*>(rp + on);

                    // ---- C: phase1(t): D-blur for d-pair -> planes ----
                    v2f muA=(v2f)0.f, mmA=(v2f)0.f, muB=(v2f)0.f, mmB=(v2f)0.f;
                    float m12A=0.f, m12B=0.f;
                    if (!dedge) {
                        const float* r0 = &raw[rawRd + p_rbase];
#pragma unroll
                        for (int j = 0; j < 12; ++j) {
                            v2f sr = *reinterpret_cast<const v2f*>(r0 + 2*j);
                            if (j < 11) {
                                v2f p = pk_mul(sr, wpk[j]);
                                pk_add_acc(muA, p);
                                pk_fma_acc(mmA, p, sr);
                                m12A = fmaf(p.x, sr.y, m12A);
                            }
                            if (j > 0) {
                                v2f p = pk_mul(sr, wpk[j-1]);
                                pk_add_acc(muB, p);
                                pk_fma_acc(mmB, p, sr);
                                m12B = fmaf(p.x, sr.y, m12B);
                            }
                        }
                    } else {
                        const float* r0 = &raw[rawRd + p_wp*RS];
#pragma unroll
                        for (int j = 0; j < 12; ++j) {
                            v2f sr = *reinterpret_cast<const v2f*>(r0 + eoff[j]);
                            if (j < 11) {
                                v2f p = pk_mul(sr, wpk[j]);
                                pk_add_acc(muA, p);
                                pk_fma_acc(mmA, p, sr);
                                m12A = fmaf(p.x, sr.y, m12A);
                            }
                            if (j > 0) {
                                v2f p = pk_mul(sr, wpk[j-1]);
                                pk_add_acc(muB, p);
                                pk_fma_acc(mmB, p, sr);
                                m12B = fmaf(p.x, sr.y, m12B);
                            }
                        }
                    }
                    // fused plane writes: 2x b128 + 1x b64 (bank-balanced)
                    v4f st01; st01.x=muA.x; st01.y=muA.y; st01.z=muB.x; st01.w=muB.y;
                    v4f st23; st23.x=mmA.x; st23.y=mmA.y; st23.z=mmB.x; st23.w=mmB.y;
                    *reinterpret_cast<v4f*>(&pl01[po01 + pA01]) = st01;
                    *reinterpret_cast<v4f*>(&pl23[po01 + pA01]) = st23;
                    v2f st4; st4.x = m12A; st4.y = m12B;
                    *reinterpret_cast<v2f*>(&pl4[po4 + pA4])    = st4;
                }

                __syncthreads();                 // the ONLY barrier per step

                // ---- E: phase2(t): d-pair W-blur (b128 taps) + ring + SSIM ----
                if (p2act) {
                    v2f v01A=(v2f)0.f, v01B=(v2f)0.f;
                    v2f v23A=(v2f)0.f, v23B=(v2f)0.f;
                    v2f v4p =(v2f)0.f;
                    const float* q01 = &pl01[po01 + q01b];
                    const float* q23 = &pl23[po01 + q01b];
                    const float* q4  = &pl4 [po4  + q4b];
#pragma unroll
                    for (int k = 0; k < KS; ++k) {
                        v4f q = *reinterpret_cast<const v4f*>(q01 + k*P01S);
                        v4f r = *reinterpret_cast<const v4f*>(q23 + k*P01S);
                        v2f m = *reinterpret_cast<const v2f*>(q4  + k*P4S);
                        v2f qlo = __builtin_shufflevector(q, q, 0, 1);
                        v2f qhi = __builtin_shufflevector(q, q, 2, 3);
                        v2f rlo = __builtin_shufflevector(r, r, 0, 1);
                        v2f rhi = __builtin_shufflevector(r, r, 2, 3);
                        pk_fma_acc(v01A, qlo, wpk[k]);
                        pk_fma_acc(v01B, qhi, wpk[k]);
                        pk_fma_acc(v23A, rlo, wpk[k]);
                        pk_fma_acc(v23B, rhi, wpk[k]);
                        pk_fma_acc(v4p,  m,   wpk[k]);
                    }
#pragma unroll
                    for (int m = 0; m < 11; ++m) {
                        const int slot = (ts + m) % 11;   // static after unroll
                        v2f wt = wpk[10 - m];
                        pk_fma_acc(a01A[slot], v01A, wt);
                        pk_fma_acc(a01B[slot], v01B, wt);
                        pk_fma_acc(a23A[slot], v23A, wt);
                        pk_fma_acc(a23B[slot], v23B, wt);
                        pk_fma_acc(a4[slot],   v4p,  wt);
                    }
                    if (t >= 10) {                        // emit h = h0 - 10 + t
                        const float C1 = 1e-4f, C2 = 9e-4f;
                        {   // output d = d0 + 2*dp
                            float mu1 = a01A[ts].x, mu2 = a01A[ts].y;
                            float m11 = a23A[ts].x, m22 = a23A[ts].y, m12 = a4[ts].x;
                            float mu1sq = mu1*mu1, mu2sq = mu2*mu2, mu12 = mu1*mu2;
                            float s1 = m11 - mu1sq, s2 = m22 - mu2sq, s12 = m12 - mu12;
                            float num = (2.f*mu12 + C1) * (2.f*s12 + C2);
                            float den = (mu1sq + mu2sq + C1) * (s1 + s2 + C2) + 1e-12f;
                            float inv = __builtin_amdgcn_rcpf(den);
                            inv = inv * (2.0f - den * inv);
                            ssum = fmaf(num, inv, ssum);
                        }
                        {   // output d = d0 + 2*dp + 1
                            float mu1 = a01B[ts].x, mu2 = a01B[ts].y;
                            float m11 = a23B[ts].x, m22 = a23B[ts].y, m12 = a4[ts].y;
                            float mu1sq = mu1*mu1, mu2sq = mu2*mu2, mu12 = mu1*mu2;
                            float s1 = m11 - mu1sq, s2 = m22 - mu2sq, s12 = m12 - mu12;
                            float num = (2.f*mu12 + C1) * (2.f*s12 + C2);
                            float den = (mu1sq + mu2sq + C1) * (s1 + s2 + C2) + 1e-12f;
                            float inv = __builtin_amdgcn_rcpf(den);
                            inv = inv * (2.0f - den * inv);
                            ssum = fmaf(num, inv, ssum);
                        }
                    }
                    a01A[ts] = (v2f)0.f; a01B[ts] = (v2f)0.f;
                    a23A[ts] = (v2f)0.f; a23B[ts] = (v2f)0.f; a4[ts] = (v2f)0.f;
                }

                rawRd ^= RAW_W; rawWr ^= RAW_W; po01 ^= P01_W; po4 ^= P4_W;
            }
        }
    }

    // ---- block reduction, one atomic per block ----
#pragma unroll
    for (int off = 32; off > 0; off >>= 1)
        ssum += __shfl_down(ssum, off, 64);
    __shared__ float lsum[4];
    int lane = tid & 63, wid = tid >> 6;
    if (lane == 0) lsum[wid] = ssum;
    __syncthreads();
    if (tid == 0)
        atomicAdd(out, -(lsum[0]+lsum[1]+lsum[2]+lsum[3]) * scale);
}

extern "C" void kernel_launch(void* const* d_in, const int* in_sizes, int n_in,
                              void* d_out, int out_size, void* d_ws, size_t ws_size,
                              hipStream_t stream) {
    const float* src = (const float*)d_in[0];
    const float* ref = (const float*)d_in[1];
    float* out = (float*)d_out;

    Wts wts;
    {
        double g[KS], s = 0.0;
        for (int i = 0; i < KS; ++i) {
            double a = (double)i - (KS - 1) / 2.0;
            g[i] = exp(-(a * a) / (2.0 * 1.5 * 1.5));
            s += g[i];
        }
        for (int i = 0; i < KS; ++i) wts.w[i] = (float)(g[i] / s);
    }

    const float scale = 1.0f / (float)NTOT;

    init_out<<<1, 64, 0, stream>>>(out);
    const int g = NBATCH * (HH/HT) * (WW/WT) * (DD/DT);   // 1000
    fused<<<g, 256, 0, stream>>>(src, ref, out, wts, scale);
}

// Round 10
// 202.532 us; speedup vs baseline: 1.0551x; 1.0551x over previous
//
#include <hip/hip_runtime.h>
#include <math.h>

#define HH 160
#define WW 160
#define DD 160
#define VOL (HH*WW*DD)          // 4,096,000
#define KS 11
#define PAD 5
#define NBATCH 2
#define NTOT (NBATCH*VOL)

// fused tile geometry
#define WT 16                    // w outputs per block
#define DT 16                    // d outputs per block
#define HT 32                    // h outputs per block (delay-line walk)
#define WPN (WT + 2*PAD)         // 26 w rows incl. halo
#define NSTEP (HT + 2*PAD)       // 42
// LDS strides (words) — ONLY r6-proven access-shape classes:
//   b64 reads at even offset 2*lane_d with ODD-ish row stride (38): balanced
//   b32 reads/writes at stride 16/17: <=4-way minority
#define RS 74                    // raw row (r6-proven)
#define P01S 38                  // plane row (r6-proven)
#define P4S 17                   // c4 plane row
#define RAW_W (WPN*RS)           // 1924 words per raw buffer
#define P01_W (WPN*P01S)         // 988
#define P4_W  (WPN*P4S)          // 442

typedef float v2f __attribute__((ext_vector_type(2)));
typedef float v4f __attribute__((ext_vector_type(4)));

struct Wts { float w[KS]; };

__device__ __forceinline__ int mirror(int i, int n) {
    if (i < 0) i = -i;
    if (i >= n) i = 2*n - 2 - i;
    return i;
}

// tied VOP3P asm: in-place accumulate, no result-copy movs
__device__ __forceinline__ void pk_fma_acc(v2f& c, v2f a, v2f b) {
    asm("v_pk_fma_f32 %0, %1, %2, %0" : "+v"(c) : "v"(a), "v"(b));
}
__device__ __forceinline__ void pk_add_acc(v2f& c, v2f a) {
    asm("v_pk_add_f32 %0, %0, %1" : "+v"(c) : "v"(a));
}
__device__ __forceinline__ v2f pk_mul(v2f a, v2f b) {
    v2f d; asm("v_pk_mul_f32 %0, %1, %2" : "=v"(d) : "v"(a), "v"(b)); return d;
}

__global__ void init_out(float* out) {
    if (threadIdx.x == 0 && blockIdx.x == 0) out[0] = 1.0f;
}

// Fully fused 3D SSIM.
// Round-9 resubmission (r9 bench was an infra failure, not a kernel verdict):
// r6 (115us champion) + phase2 W-PAIR: 128 threads x 2 w-adjacent outputs
// from the 12-row tap union -> phase2 LDS ops 33->18 per output and bytes
// 220->120 B/output, using ONLY r6-proven b64/b32 access shapes (r8's
// wide-op patterns tripled conflicts: suspected compiler split-to-b32).
__global__ __launch_bounds__(256) void fused(const float* __restrict__ src,
                                             const float* __restrict__ ref,
                                             float* __restrict__ out,
                                             Wts wts, float scale) {
    __shared__ __align__(16) float raw [2*RAW_W];   // (s,r) interleaved window
    __shared__ __align__(16) float pl01[2*P01_W];   // (mu1,mu2) pairs
    __shared__ __align__(16) float pl23[2*P01_W];   // (m11,m22)
    __shared__ __align__(16) float pl4 [2*P4_W];    // m12

    const int bx  = blockIdx.x;
    const int dt_ = bx % (DD/DT);
    const int wt_ = (bx / (DD/DT)) % (WW/WT);
    const int ht_ = (bx / ((DD/DT)*(WW/WT))) % (HH/HT);
    const int b   = bx / ((DD/DT)*(WW/WT)*(HH/HT));
    const int d0 = dt_*DT, w0 = wt_*WT, h0 = ht_*HT;

    const int  dbase = (d0 == 0) ? 0 : ((d0 == DD-DT) ? DD-32 : d0-8);
    const bool dedge = (d0 == 0) || (d0 == DD-DT);
    const bool hedge = (ht_ == 0) || (ht_ == HH/HT - 1);

    const int tid = threadIdx.x;
    const float* __restrict__ sp = src + (size_t)b*VOL;
    const float* __restrict__ rp = ref + (size_t)b*VOL;

    // ---- stage identity: 208 threads, (row swp, quad sq) ----
    const bool sact = (tid < WPN*8);                 // 208: stage AND phase1
    const int  swp = tid >> 3, sq = tid & 7;
    const int  sgoff  = mirror(w0 - PAD + (sact ? swp : 0), WW)*DD + dbase + sq*4;
    const int  srawof = swp*RS + sq*8;

    // ---- phase1 identity: thread (p_wp, p_dlp) owns points d=2dlp, 2dlp+1 ----
    const int  p_wp  = tid >> 3;                     // 0..25
    const int  p_dlp = tid & 7;                      // 0..7
    const int  pA01  = p_wp*P01S + 4*p_dlp;
    const int  pA4   = p_wp*P4S  + 2*p_dlp;
    const int  p_rbase = p_wp*RS + 6 + 4*p_dlp;      // interior tap base

    int eoff[12];
    if (dedge) {
#pragma unroll
        for (int j = 0; j < 12; ++j)
            eoff[j] = 2*(mirror(d0 + 2*p_dlp - PAD + j, DD) - dbase);
    }

    // ---- phase2 identity: 128 threads, outputs (w0+2wl2 / +1, d0+d2) ----
    const bool p2act = (tid < 128);
    const int  d2  = tid & 15;
    const int  wl2 = (tid >> 4) & 7;                 // output rows 2wl2, 2wl2+1
    const int  q01b = (2*wl2)*P01S + 2*d2;           // j=0 row base
    const int  q4b  = (2*wl2)*P4S  + d2;

    v2f wpk[KS];
#pragma unroll
    for (int k = 0; k < KS; ++k) { wpk[k].x = wts.w[k]; wpk[k].y = wts.w[k]; }

    // H delay-line rings for the two outputs (A = row 2wl2, B = row 2wl2+1)
    v2f a01A[KS], a01B[KS], a23A[KS], a23B[KS];
    float a4A[KS], a4B[KS];
#pragma unroll
    for (int s = 0; s < KS; ++s) {
        a01A[s] = (v2f)0.f; a01B[s] = (v2f)0.f;
        a23A[s] = (v2f)0.f; a23B[s] = (v2f)0.f;
        a4A[s] = 0.f; a4B[s] = 0.f;
    }

    // ---- prologue: stage step 0 into raw half 0, prefetch step 1 ----
    v4f ra = (v4f)0.f, rb_ = (v4f)0.f;
    if (sact) {
        int hm0 = h0 - PAD;           if (hedge) hm0 = mirror(hm0, HH);
        const size_t o0 = (size_t)hm0*(WW*DD) + sgoff;
        ra  = *reinterpret_cast<const v4f*>(sp + o0);
        rb_ = *reinterpret_cast<const v4f*>(rp + o0);
        v2f p0, p1, p2, p3;
        p0.x=ra.x; p0.y=rb_.x;  p1.x=ra.y; p1.y=rb_.y;
        p2.x=ra.z; p2.y=rb_.z;  p3.x=ra.w; p3.y=rb_.w;
        *reinterpret_cast<v2f*>(&raw[srawof])     = p0;
        *reinterpret_cast<v2f*>(&raw[srawof + 2]) = p1;
        *reinterpret_cast<v2f*>(&raw[srawof + 4]) = p2;
        *reinterpret_cast<v2f*>(&raw[srawof + 6]) = p3;
        int hm1 = h0 - PAD + 1;       if (hedge) hm1 = mirror(hm1, HH);
        const size_t o1 = (size_t)hm1*(WW*DD) + sgoff;
        ra  = *reinterpret_cast<const v4f*>(sp + o1);
        rb_ = *reinterpret_cast<const v4f*>(rp + o1);
    }
    __syncthreads();

    float ssum = 0.f;
    int rawRd = 0, rawWr = RAW_W, po01 = 0, po4 = 0;

#pragma unroll 1
    for (int tb = 0; tb < 44; tb += 11) {
#pragma unroll
        for (int ts = 0; ts < 11; ++ts) {
            const int t = tb + ts;
            if (t < NSTEP) {                     // block-uniform
                if (sact) {
                    // ---- A: stage step t+1 (prefetched regs) -> raw[rawWr] ----
                    v2f p0, p1, p2, p3;
                    p0.x=ra.x; p0.y=rb_.x;  p1.x=ra.y; p1.y=rb_.y;
                    p2.x=ra.z; p2.y=rb_.z;  p3.x=ra.w; p3.y=rb_.w;
                    *reinterpret_cast<v2f*>(&raw[rawWr + srawof])     = p0;
                    *reinterpret_cast<v2f*>(&raw[rawWr + srawof + 2]) = p1;
                    *reinterpret_cast<v2f*>(&raw[rawWr + srawof + 4]) = p2;
                    *reinterpret_cast<v2f*>(&raw[rawWr + srawof + 6]) = p3;
                    // ---- B: re-issue prefetch for step t+2 ----
                    int hn = h0 - PAD + t + 2;  if (hedge) hn = mirror(hn, HH);
                    const size_t on = (size_t)hn*(WW*DD) + sgoff;
                    ra  = *reinterpret_cast<const v4f*>(sp + on);
                    rb_ = *reinterpret_cast<const v4f*>(rp + on);

                    // ---- C: phase1(t): D-blur for d-pair -> planes ----
                    v2f muA=(v2f)0.f, mmA=(v2f)0.f, muB=(v2f)0.f, mmB=(v2f)0.f;
                    float m12A=0.f, m12B=0.f;
                    if (!dedge) {
                        const float* r0 = &raw[rawRd + p_rbase];
#pragma unroll
                        for (int j = 0; j < 12; ++j) {
                            v2f sr = *reinterpret_cast<const v2f*>(r0 + 2*j);
                            if (j < 11) {
                                v2f p = pk_mul(sr, wpk[j]);
                                pk_add_acc(muA, p);
                                pk_fma_acc(mmA, p, sr);
                                m12A = fmaf(p.x, sr.y, m12A);
                            }
                            if (j > 0) {
                                v2f p = pk_mul(sr, wpk[j-1]);
                                pk_add_acc(muB, p);
                                pk_fma_acc(mmB, p, sr);
                                m12B = fmaf(p.x, sr.y, m12B);
                            }
                        }
                    } else {
                        const float* r0 = &raw[rawRd + p_wp*RS];
#pragma unroll
                        for (int j = 0; j < 12; ++j) {
                            v2f sr = *reinterpret_cast<const v2f*>(r0 + eoff[j]);
                            if (j < 11) {
                                v2f p = pk_mul(sr, wpk[j]);
                                pk_add_acc(muA, p);
                                pk_fma_acc(mmA, p, sr);
                                m12A = fmaf(p.x, sr.y, m12A);
                            }
                            if (j > 0) {
                                v2f p = pk_mul(sr, wpk[j-1]);
                                pk_add_acc(muB, p);
                                pk_fma_acc(mmB, p, sr);
                                m12B = fmaf(p.x, sr.y, m12B);
                            }
                        }
                    }
                    // plane writes: r6-proven shapes (4x b64 + 2x b32)
                    *reinterpret_cast<v2f*>(&pl01[po01 + pA01])     = muA;
                    *reinterpret_cast<v2f*>(&pl01[po01 + pA01 + 2]) = muB;
                    *reinterpret_cast<v2f*>(&pl23[po01 + pA01])     = mmA;
                    *reinterpret_cast<v2f*>(&pl23[po01 + pA01 + 2]) = mmB;
                    pl4[po4 + pA4]     = m12A;
                    pl4[po4 + pA4 + 1] = m12B;
                }

                __syncthreads();                 // the ONLY barrier per step

                // ---- E: phase2(t): w-pair W-blur (12-row union) + rings ----
                if (p2act) {
                    const float* q01 = &pl01[po01 + q01b];
                    const float* q23 = &pl23[po01 + q01b];
                    const float* q4  = &pl4 [po4  + q4b];
                    v2f v01A, v23A; float v4A;
                    v2f v01B = (v2f)0.f, v23B = (v2f)0.f; float v4B = 0.f;
                    {   // row 0: A only
                        v2f c01 = *reinterpret_cast<const v2f*>(q01);
                        v2f c23 = *reinterpret_cast<const v2f*>(q23);
                        float c4 = q4[0];
                        v01A = pk_mul(c01, wpk[0]);
                        v23A = pk_mul(c23, wpk[0]);
                        v4A  = wts.w[0]*c4;
                    }
#pragma unroll
                    for (int j = 1; j <= 10; ++j) {   // rows 1..10: both outputs
                        v2f c01 = *reinterpret_cast<const v2f*>(q01 + j*P01S);
                        v2f c23 = *reinterpret_cast<const v2f*>(q23 + j*P01S);
                        float c4 = q4[j*P4S];
                        pk_fma_acc(v01A, c01, wpk[j]);
                        pk_fma_acc(v23A, c23, wpk[j]);
                        v4A = fmaf(wts.w[j], c4, v4A);
                        pk_fma_acc(v01B, c01, wpk[j-1]);
                        pk_fma_acc(v23B, c23, wpk[j-1]);
                        v4B = fmaf(wts.w[j-1], c4, v4B);
                    }
                    {   // row 11: B only
                        v2f c01 = *reinterpret_cast<const v2f*>(q01 + 11*P01S);
                        v2f c23 = *reinterpret_cast<const v2f*>(q23 + 11*P01S);
                        float c4 = q4[11*P4S];
                        pk_fma_acc(v01B, c01, wpk[10]);
                        pk_fma_acc(v23B, c23, wpk[10]);
                        v4B = fmaf(wts.w[10], c4, v4B);
                    }
#pragma unroll
                    for (int m = 0; m < 11; ++m) {
                        const int slot = (ts + m) % 11;   // static after unroll
                        v2f wt = wpk[10 - m];
                        pk_fma_acc(a01A[slot], v01A, wt);
                        pk_fma_acc(a23A[slot], v23A, wt);
                        pk_fma_acc(a01B[slot], v01B, wt);
                        pk_fma_acc(a23B[slot], v23B, wt);
                        a4A[slot] = fmaf(wt.x, v4A, a4A[slot]);
                        a4B[slot] = fmaf(wt.x, v4B, a4B[slot]);
                    }
                    if (t >= 10) {                        // emit h = h0 - 10 + t
                        const float C1 = 1e-4f, C2 = 9e-4f;
                        {   // output (2wl2, d2)
                            float mu1 = a01A[ts].x, mu2 = a01A[ts].y;
                            float m11 = a23A[ts].x, m22 = a23A[ts].y, m12 = a4A[ts];
                            float mu1sq = mu1*mu1, mu2sq = mu2*mu2, mu12 = mu1*mu2;
                            float s1 = m11 - mu1sq, s2 = m22 - mu2sq, s12 = m12 - mu12;
                            float num = (2.f*mu12 + C1) * (2.f*s12 + C2);
                            float den = (mu1sq + mu2sq + C1) * (s1 + s2 + C2) + 1e-12f;
                            float inv = __builtin_amdgcn_rcpf(den);
                            inv = inv * (2.0f - den * inv);
                            ssum = fmaf(num, inv, ssum);
                        }
                        {   // output (2wl2+1, d2)
                            float mu1 = a01B[ts].x, mu2 = a01B[ts].y;
                            float m11 = a23B[ts].x, m22 = a23B[ts].y, m12 = a4B[ts];
                            float mu1sq = mu1*mu1, mu2sq = mu2*mu2, mu12 = mu1*mu2;
                            float s1 = m11 - mu1sq, s2 = m22 - mu2sq, s12 = m12 - mu12;
                            float num = (2.f*mu12 + C1) * (2.f*s12 + C2);
                            float den = (mu1sq + mu2sq + C1) * (s1 + s2 + C2) + 1e-12f;
                            float inv = __builtin_amdgcn_rcpf(den);
                            inv = inv * (2.0f - den * inv);
                            ssum = fmaf(num, inv, ssum);
                        }
                    }
                    a01A[ts] = (v2f)0.f; a23A[ts] = (v2f)0.f;
                    a01B[ts] = (v2f)0.f; a23B[ts] = (v2f)0.f;
                    a4A[ts] = 0.f; a4B[ts] = 0.f;
                }

                rawRd ^= RAW_W; rawWr ^= RAW_W; po01 ^= P01_W; po4 ^= P4_W;
            }
        }
    }

    // ---- block reduction, one atomic per block ----
#pragma unroll
    for (int off = 32; off > 0; off >>= 1)
        ssum += __shfl_down(ssum, off, 64);
    __shared__ float lsum[4];
    int lane = tid & 63, wid = tid >> 6;
    if (lane == 0) lsum[wid] = ssum;
    __syncthreads();
    if (tid == 0)
        atomicAdd(out, -(lsum[0]+lsum[1]+lsum[2]+lsum[3]) * scale);
}

extern "C" void kernel_launch(void* const* d_in, const int* in_sizes, int n_in,
                              void* d_out, int out_size, void* d_ws, size_t ws_size,
                              hipStream_t stream) {
    const float* src = (const float*)d_in[0];
    const float* ref = (const float*)d_in[1];
    float* out = (float*)d_out;

    Wts wts;
    {
        double g[KS], s = 0.0;
        for (int i = 0; i < KS; ++i) {
            double a = (double)i - (KS - 1) / 2.0;
            g[i] = exp(-(a * a) / (2.0 * 1.5 * 1.5));
            s += g[i];
        }
        for (int i = 0; i < KS; ++i) wts.w[i] = (float)(g[i] / s);
    }

    const float scale = 1.0f / (float)NTOT;

    init_out<<<1, 64, 0, stream>>>(out);
    const int g = NBATCH * (HH/HT) * (WW/WT) * (DD/DT);   // 1000
    fused<<<g, 256, 0, stream>>>(src, ref, out, wts, scale);
}

// Round 11
// 198.862 us; speedup vs baseline: 1.0745x; 1.0185x over previous
//
#include <hip/hip_runtime.h>
#include <math.h>

#define HH 160
#define WW 160
#define DD 160
#define VOL (HH*WW*DD)          // 4,096,000
#define KS 11
#define PAD 5
#define NBATCH 2
#define NTOT (NBATCH*VOL)

// fused tile geometry
#define WT 16                    // w outputs per block
#define DT 16                    // d outputs per block
#define HT 16                    // h outputs per block (r11: halved -> 2000 blocks)
#define WPN (WT + 2*PAD)         // 26 w rows incl. halo
#define NSTEP (HT + 2*PAD)       // 26
// LDS strides (words) — r6-proven access-shape classes only
#define RS 74                    // raw row (r6-proven)
#define P01S 38                  // plane row (r6-proven)
#define P4S 17                   // c4 plane row (r6-proven)
#define RAW_W (WPN*RS)           // 1924 words (SINGLE buffer now)
#define P01_W (WPN*P01S)         // 988
#define P4_W  (WPN*P4S)          // 442
// total LDS = (1924+988+988+442)*4 = 17368 B -> VGPR-capped 6 blocks/CU

typedef float v2f __attribute__((ext_vector_type(2)));
typedef float v4f __attribute__((ext_vector_type(4)));

struct Wts { float w[KS]; };

__device__ __forceinline__ int mirror(int i, int n) {
    if (i < 0) i = -i;
    if (i >= n) i = 2*n - 2 - i;
    return i;
}

// tied VOP3P asm: in-place accumulate, no result-copy movs
__device__ __forceinline__ void pk_fma_acc(v2f& c, v2f a, v2f b) {
    asm("v_pk_fma_f32 %0, %1, %2, %0" : "+v"(c) : "v"(a), "v"(b));
}
__device__ __forceinline__ void pk_add_acc(v2f& c, v2f a) {
    asm("v_pk_add_f32 %0, %0, %1" : "+v"(c) : "v"(a));
}
__device__ __forceinline__ v2f pk_mul(v2f a, v2f b) {
    v2f d; asm("v_pk_mul_f32 %0, %1, %2" : "=v"(d) : "v"(a), "v"(b)); return d;
}

__global__ void init_out(float* out) {
    if (threadIdx.x == 0 && blockIdx.x == 0) out[0] = 1.0f;
}

// Fully fused 3D SSIM.
// Round-11 = r6 phase structure (balanced 256-thread phase2, proven LDS shapes)
// + occupancy attack: r10 showed the kernel is latency-bound on the per-step
// critical chain with grid-capped ~4 blocks/CU. HT 32->16 doubles the grid to
// 2000; single-buffered raw+planes (2 barriers/step, hazard-audited) cuts LDS
// 34.8->17.4 KB so residency is VGPR-capped at 6 blocks/CU (24/32 wave slots).
__global__ __launch_bounds__(256) void fused(const float* __restrict__ src,
                                             const float* __restrict__ ref,
                                             float* __restrict__ out,
                                             Wts wts, float scale) {
    __shared__ __align__(16) float raw [RAW_W];   // (s,r) interleaved window
    __shared__ __align__(16) float pl01[P01_W];   // (mu1,mu2) pairs
    __shared__ __align__(16) float pl23[P01_W];   // (m11,m22)
    __shared__ __align__(16) float pl4 [P4_W];    // m12

    const int bx  = blockIdx.x;
    const int dt_ = bx % (DD/DT);
    const int wt_ = (bx / (DD/DT)) % (WW/WT);
    const int ht_ = (bx / ((DD/DT)*(WW/WT))) % (HH/HT);
    const int b   = bx / ((DD/DT)*(WW/WT)*(HH/HT));
    const int d0 = dt_*DT, w0 = wt_*WT, h0 = ht_*HT;

    const int  dbase = (d0 == 0) ? 0 : ((d0 == DD-DT) ? DD-32 : d0-8);
    const bool dedge = (d0 == 0) || (d0 == DD-DT);
    const bool hedge = (ht_ == 0) || (ht_ == HH/HT - 1);

    const int tid = threadIdx.x;
    const float* __restrict__ sp = src + (size_t)b*VOL;
    const float* __restrict__ rp = ref + (size_t)b*VOL;

    // ---- stage identity: 208 threads, (row swp, quad sq) ----
    const bool sact = (tid < WPN*8);                 // 208: stage AND phase1
    const int  swp = tid >> 3, sq = tid & 7;
    const int  sgoff  = mirror(w0 - PAD + (sact ? swp : 0), WW)*DD + dbase + sq*4;
    const int  srawof = swp*RS + sq*8;

    // ---- phase1 identity: thread (p_wp, p_dlp) owns points d=2dlp, 2dlp+1 ----
    const int  p_wp  = tid >> 3;                     // 0..25
    const int  p_dlp = tid & 7;                      // 0..7
    const int  pA01  = p_wp*P01S + 4*p_dlp;
    const int  pA4   = p_wp*P4S  + 2*p_dlp;
    const int  p_rbase = p_wp*RS + 6 + 4*p_dlp;      // interior tap base

    int eoff[12];
    if (dedge) {
#pragma unroll
        for (int j = 0; j < 12; ++j)
            eoff[j] = 2*(mirror(d0 + 2*p_dlp - PAD + j, DD) - dbase);
    }

    // ---- phase2 identity: 256 threads, one output column (w0+wl, d0+dl2) ----
    const int wl = tid >> 4, dl2 = tid & 15;

    v2f wpk[KS];
#pragma unroll
    for (int k = 0; k < KS; ++k) { wpk[k].x = wts.w[k]; wpk[k].y = wts.w[k]; }

    v2f acc01[KS], acc23[KS];
    float acc4[KS];
#pragma unroll
    for (int s = 0; s < KS; ++s) {
        acc01[s] = (v2f)0.f; acc23[s] = (v2f)0.f; acc4[s] = 0.f;
    }

    // ---- prologue: stage step 0 into raw, prefetch step 1 ----
    v4f ra = (v4f)0.f, rb_ = (v4f)0.f;
    if (sact) {
        int hm0 = h0 - PAD;           if (hedge) hm0 = mirror(hm0, HH);
        const size_t o0 = (size_t)hm0*(WW*DD) + sgoff;
        ra  = *reinterpret_cast<const v4f*>(sp + o0);
        rb_ = *reinterpret_cast<const v4f*>(rp + o0);
        v2f p0, p1, p2, p3;
        p0.x=ra.x; p0.y=rb_.x;  p1.x=ra.y; p1.y=rb_.y;
        p2.x=ra.z; p2.y=rb_.z;  p3.x=ra.w; p3.y=rb_.w;
        *reinterpret_cast<v2f*>(&raw[srawof])     = p0;
        *reinterpret_cast<v2f*>(&raw[srawof + 2]) = p1;
        *reinterpret_cast<v2f*>(&raw[srawof + 4]) = p2;
        *reinterpret_cast<v2f*>(&raw[srawof + 6]) = p3;
        int hm1 = h0 - PAD + 1;       if (hedge) hm1 = mirror(hm1, HH);
        const size_t o1 = (size_t)hm1*(WW*DD) + sgoff;
        ra  = *reinterpret_cast<const v4f*>(sp + o1);
        rb_ = *reinterpret_cast<const v4f*>(rp + o1);
    }
    __syncthreads();

    float ssum = 0.f;

#pragma unroll 1
    for (int tb = 0; tb < 33; tb += 11) {
#pragma unroll
        for (int ts = 0; ts < 11; ++ts) {
            const int t = tb + ts;
            if (t < NSTEP) {                     // block-uniform
                // ---- phase1(t): D-blur for d-pair from raw -> planes ----
                if (sact) {
                    v2f muA=(v2f)0.f, mmA=(v2f)0.f, muB=(v2f)0.f, mmB=(v2f)0.f;
                    float m12A=0.f, m12B=0.f;
                    if (!dedge) {
                        const float* r0 = &raw[p_rbase];
#pragma unroll
                        for (int j = 0; j < 12; ++j) {
                            v2f sr = *reinterpret_cast<const v2f*>(r0 + 2*j);
                            if (j < 11) {
                                v2f p = pk_mul(sr, wpk[j]);
                                pk_add_acc(muA, p);
                                pk_fma_acc(mmA, p, sr);
                                m12A = fmaf(p.x, sr.y, m12A);
                            }
                            if (j > 0) {
                                v2f p = pk_mul(sr, wpk[j-1]);
                                pk_add_acc(muB, p);
                                pk_fma_acc(mmB, p, sr);
                                m12B = fmaf(p.x, sr.y, m12B);
                            }
                        }
                    } else {
                        const float* r0 = &raw[p_wp*RS];
#pragma unroll
                        for (int j = 0; j < 12; ++j) {
                            v2f sr = *reinterpret_cast<const v2f*>(r0 + eoff[j]);
                            if (j < 11) {
                                v2f p = pk_mul(sr, wpk[j]);
                                pk_add_acc(muA, p);
                                pk_fma_acc(mmA, p, sr);
                                m12A = fmaf(p.x, sr.y, m12A);
                            }
                            if (j > 0) {
                                v2f p = pk_mul(sr, wpk[j-1]);
                                pk_add_acc(muB, p);
                                pk_fma_acc(mmB, p, sr);
                                m12B = fmaf(p.x, sr.y, m12B);
                            }
                        }
                    }
                    // plane writes: r6-proven shapes (4x b64 + 2x b32)
                    *reinterpret_cast<v2f*>(&pl01[pA01])     = muA;
                    *reinterpret_cast<v2f*>(&pl01[pA01 + 2]) = muB;
                    *reinterpret_cast<v2f*>(&pl23[pA01])     = mmA;
                    *reinterpret_cast<v2f*>(&pl23[pA01 + 2]) = mmB;
                    pl4[pA4]     = m12A;
                    pl4[pA4 + 1] = m12B;
                }

                __syncthreads();                 // barrier A: planes ready,
                                                 // raw reads of step t drained

                // ---- stage(t+1) into raw (safe: phase1(t) reads done) ----
                if (sact) {
                    v2f p0, p1, p2, p3;
                    p0.x=ra.x; p0.y=rb_.x;  p1.x=ra.y; p1.y=rb_.y;
                    p2.x=ra.z; p2.y=rb_.z;  p3.x=ra.w; p3.y=rb_.w;
                    *reinterpret_cast<v2f*>(&raw[srawof])     = p0;
                    *reinterpret_cast<v2f*>(&raw[srawof + 2]) = p1;
                    *reinterpret_cast<v2f*>(&raw[srawof + 4]) = p2;
                    *reinterpret_cast<v2f*>(&raw[srawof + 6]) = p3;
                    // re-issue prefetch for step t+2 (in-bounds: interior
                    // blocks max h0+22 <= 150; hedge mirrored)
                    int hn = h0 - PAD + t + 2;  if (hedge) hn = mirror(hn, HH);
                    const size_t on = (size_t)hn*(WW*DD) + sgoff;
                    ra  = *reinterpret_cast<const v4f*>(sp + on);
                    rb_ = *reinterpret_cast<const v4f*>(rp + on);
                }

                // ---- phase2(t): W-blur from planes + H-ring + SSIM ----
                {
                    v2f v01 = (v2f)0.f, v23 = (v2f)0.f;
                    float v4v = 0.f;
                    const float* q01 = &pl01[wl*P01S + 2*dl2];
                    const float* q23 = &pl23[wl*P01S + 2*dl2];
                    const float* q4  = &pl4 [wl*P4S  + dl2];
#pragma unroll
                    for (int k = 0; k < KS; ++k) {
                        v2f w = wpk[k];
                        pk_fma_acc(v01, *reinterpret_cast<const v2f*>(q01 + k*P01S), w);
                        pk_fma_acc(v23, *reinterpret_cast<const v2f*>(q23 + k*P01S), w);
                        v4v = fmaf(w.x, q4[k*P4S], v4v);
                    }
#pragma unroll
                    for (int m = 0; m < 11; ++m) {
                        const int slot = (ts + m) % 11;   // static after unroll
                        v2f wt = wpk[10 - m];
                        pk_fma_acc(acc01[slot], v01, wt);
                        pk_fma_acc(acc23[slot], v23, wt);
                        acc4[slot]  = fmaf(wt.x, v4v, acc4[slot]);
                    }
                    if (t >= 10) {                        // emit h = h0 - 10 + t
                        float mu1 = acc01[ts].x, mu2 = acc01[ts].y;
                        float m11 = acc23[ts].x, m22 = acc23[ts].y, m12 = acc4[ts];
                        float mu1sq = mu1*mu1, mu2sq = mu2*mu2, mu12 = mu1*mu2;
                        float s1 = m11 - mu1sq, s2 = m22 - mu2sq, s12 = m12 - mu12;
                        const float C1 = 1e-4f, C2 = 9e-4f;
                        float num = (2.f*mu12 + C1) * (2.f*s12 + C2);
                        float den = (mu1sq + mu2sq + C1) * (s1 + s2 + C2) + 1e-12f;
                        float inv = __builtin_amdgcn_rcpf(den);
                        inv = inv * (2.0f - den * inv);   // 1 NR step -> ~1ulp
                        ssum = fmaf(num, inv, ssum);
                    }
                    acc01[ts] = (v2f)0.f; acc23[ts] = (v2f)0.f; acc4[ts] = 0.f;
                }

                __syncthreads();                 // barrier B: plane reads done,
                                                 // raw(t+1) visible to phase1
            }
        }
    }

    // ---- block reduction, one atomic per block ----
#pragma unroll
    for (int off = 32; off > 0; off >>= 1)
        ssum += __shfl_down(ssum, off, 64);
    __shared__ float lsum[4];
    int lane = tid & 63, wid = tid >> 6;
    if (lane == 0) lsum[wid] = ssum;
    __syncthreads();
    if (tid == 0)
        atomicAdd(out, -(lsum[0]+lsum[1]+lsum[2]+lsum[3]) * scale);
}

extern "C" void kernel_launch(void* const* d_in, const int* in_sizes, int n_in,
                              void* d_out, int out_size, void* d_ws, size_t ws_size,
                              hipStream_t stream) {
    const float* src = (const float*)d_in[0];
    const float* ref = (const float*)d_in[1];
    float* out = (float*)d_out;

    Wts wts;
    {
        double g[KS], s = 0.0;
        for (int i = 0; i < KS; ++i) {
            double a = (double)i - (KS - 1) / 2.0;
            g[i] = exp(-(a * a) / (2.0 * 1.5 * 1.5));
            s += g[i];
        }
        for (int i = 0; i < KS; ++i) wts.w[i] = (float)(g[i] / s);
    }

    const float scale = 1.0f / (float)NTOT;

    init_out<<<1, 64, 0, stream>>>(out);
    const int g = NBATCH * (HH/HT) * (WW/WT) * (DD/DT);   // 2*10*10*10 = 2000
    fused<<<g, 256, 0, stream>>>(src, ref, out, wts, scale);
}

// Round 12
// 179.547 us; speedup vs baseline: 1.1901x; 1.1076x over previous
//
#include <hip/hip_runtime.h>
#include <math.h>

#define HH 160
#define WW 160
#define DD 160
#define VOL (HH*WW*DD)          // 4,096,000
#define KS 11
#define PAD 5
#define NBATCH 2
#define NTOT (NBATCH*VOL)

// fused tile geometry
#define WT 16                    // w outputs per block
#define DT 16                    // d outputs per block
#define HT 32                    // h outputs per block (delay-line walk)
#define WPN (WT + 2*PAD)         // 26 w rows incl. halo
#define NSTEP (HT + 2*PAD)       // 42
// LDS strides (words) — bank-audited for the wave shapes below
#define RS 74                    // raw row: pair-bank 5wp+2dlp -> max 3-way (was 8-way at 68)
#define P01S 38                  // plane row: pair-bank 19wp+2dlp -> 0 in-wave collisions
#define P4S 16                   // c4 plane row: 16wl+dl2 -> exact 2-way (free)
#define RAW_W (WPN*RS)           // 1924 words per raw buffer
#define P01_W (WPN*P01S)         // 988
#define P4_W  (WPN*P4S)          // 416

typedef float v2f __attribute__((ext_vector_type(2)));
typedef float v4f __attribute__((ext_vector_type(4)));

struct Wts { float w[KS]; };

__device__ __forceinline__ int mirror(int i, int n) {
    if (i < 0) i = -i;
    if (i >= n) i = 2*n - 2 - i;
    return i;
}

// tied VOP3P asm: in-place accumulate, no result-copy movs
__device__ __forceinline__ void pk_fma_acc(v2f& c, v2f a, v2f b) {
    asm("v_pk_fma_f32 %0, %1, %2, %0" : "+v"(c) : "v"(a), "v"(b));
}
__device__ __forceinline__ void pk_add_acc(v2f& c, v2f a) {
    asm("v_pk_add_f32 %0, %0, %1" : "+v"(c) : "v"(a));
}
__device__ __forceinline__ v2f pk_mul(v2f a, v2f b) {
    v2f d; asm("v_pk_mul_f32 %0, %1, %2" : "=v"(d) : "v"(a), "v"(b)); return d;
}

__global__ void init_out(float* out) {
    if (threadIdx.x == 0 && blockIdx.x == 0) out[0] = 1.0f;
}

// Fully fused 3D SSIM — ROUND-6 CHAMPION, restored.
// Measured r6: fused 115.0-115.4 us, bench 178.9 us, VGPR 80, conflicts 6.15M,
// FETCH 202 MB, WRITE 31 KB. Post-r6 rewrites (DPP W-blur, b128 planes, w-pair
// phase2, HT=16 occupancy attack) ALL regressed 17-31%: cycle accounting shows
// this structure runs at ~90% LDS-data-path utilization (~1520 cyc/block-step
// vs 6576 CU-cycles at 3.9 blocks/CU) — its structural roofline.
// Structure: single barrier per h-step; raw window + 5-channel planes double-
// buffered in LDS; D-blur (d-pair per thread) -> W-blur -> register H-ring.
__global__ __launch_bounds__(256) void fused(const float* __restrict__ src,
                                             const float* __restrict__ ref,
                                             float* __restrict__ out,
                                             Wts wts, float scale) {
    __shared__ __align__(16) float raw [2*RAW_W];   // (s,r) interleaved window
    __shared__ __align__(16) float pl01[2*P01_W];   // (mu1,mu2)
    __shared__ __align__(16) float pl23[2*P01_W];   // (m11,m22)
    __shared__ __align__(16) float pl4 [2*P4_W];    // m12

    const int bx  = blockIdx.x;
    const int dt_ = bx % (DD/DT);
    const int wt_ = (bx / (DD/DT)) % (WW/WT);
    const int ht_ = (bx / ((DD/DT)*(WW/WT))) % (HH/HT);
    const int b   = bx / ((DD/DT)*(WW/WT)*(HH/HT));
    const int d0 = dt_*DT, w0 = wt_*WT, h0 = ht_*HT;

    // aligned 32-float raw window [dbase, dbase+32) covers all mirrored d-taps
    const int  dbase = (d0 == 0) ? 0 : ((d0 == DD-DT) ? DD-32 : d0-8);
    const bool dedge = (d0 == 0) || (d0 == DD-DT);

    const int tid = threadIdx.x;
    const float* __restrict__ sp = src + (size_t)b*VOL;
    const float* __restrict__ rp = ref + (size_t)b*VOL;

    // ---- stage identity: 208 threads, (row swp, quad sq) ----
    const bool sact = (tid < WPN*8);                 // 208: stage AND phase1
    const int  swp = tid >> 3, sq = tid & 7;
    const int  sgoff  = mirror(w0 - PAD + (sact ? swp : 0), WW)*DD + dbase + sq*4;
    const int  srawof = swp*RS + sq*8;

    // ---- phase1 identity: thread (p_wp, p_dlp) owns points d=2dlp, 2dlp+1 ----
    const int  p_wp  = tid >> 3;                     // 0..25
    const int  p_dlp = tid & 7;                      // 0..7
    const int  pA01  = p_wp*P01S + 4*p_dlp;
    const int  pA4   = p_wp*P4S  + 2*p_dlp;
    // interior-tap base: local tap start = 3 + 2dlp -> word 6 + 4dlp
    const int  p_rbase = p_wp*RS + 6 + 4*p_dlp;

    // edge-block mirrored d-tap offsets (12-tap union window), hoisted
    int eoff[12];
    if (dedge) {
#pragma unroll
        for (int j = 0; j < 12; ++j)
            eoff[j] = 2*(mirror(d0 + 2*p_dlp - PAD + j, DD) - dbase);
    }

    // ---- phase2 identity: output column (w0+wl, d0+dl2) ----
    const int wl = tid >> 4, dl2 = tid & 15;

    v2f wpk[KS];
#pragma unroll
    for (int k = 0; k < KS; ++k) { wpk[k].x = wts.w[k]; wpk[k].y = wts.w[k]; }

    v2f acc01[KS], acc23[KS];
    float acc4[KS];
#pragma unroll
    for (int s = 0; s < KS; ++s) {
        acc01[s] = (v2f)0.f; acc23[s] = (v2f)0.f; acc4[s] = 0.f;
    }

    // ---- prologue: stage step 0 into raw half 0, prefetch step 1 ----
    v4f ra = (v4f)0.f, rb_ = (v4f)0.f;
    if (sact) {
        const size_t o0 = (size_t)mirror(h0 - PAD, HH)*(WW*DD) + sgoff;
        ra  = *reinterpret_cast<const v4f*>(sp + o0);
        rb_ = *reinterpret_cast<const v4f*>(rp + o0);
        v2f p0, p1, p2, p3;
        p0.x=ra.x; p0.y=rb_.x;  p1.x=ra.y; p1.y=rb_.y;
        p2.x=ra.z; p2.y=rb_.z;  p3.x=ra.w; p3.y=rb_.w;
        *reinterpret_cast<v2f*>(&raw[srawof])     = p0;
        *reinterpret_cast<v2f*>(&raw[srawof + 2]) = p1;
        *reinterpret_cast<v2f*>(&raw[srawof + 4]) = p2;
        *reinterpret_cast<v2f*>(&raw[srawof + 6]) = p3;
        const size_t o1 = (size_t)mirror(h0 - PAD + 1, HH)*(WW*DD) + sgoff;
        ra  = *reinterpret_cast<const v4f*>(sp + o1);
        rb_ = *reinterpret_cast<const v4f*>(rp + o1);
    }
    __syncthreads();

    float ssum = 0.f;
    int rawRd = 0, rawWr = RAW_W, po01 = 0, po4 = 0;

    for (int tb = 0; tb < 44; tb += 11) {
#pragma unroll
        for (int ts = 0; ts < 11; ++ts) {
            const int t = tb + ts;
            if (t < NSTEP) {                     // block-uniform
                if (sact) {
                    // ---- A: stage step t+1 (prefetched regs) -> raw[rawWr] ----
                    v2f p0, p1, p2, p3;
                    p0.x=ra.x; p0.y=rb_.x;  p1.x=ra.y; p1.y=rb_.y;
                    p2.x=ra.z; p2.y=rb_.z;  p3.x=ra.w; p3.y=rb_.w;
                    *reinterpret_cast<v2f*>(&raw[rawWr + srawof])     = p0;
                    *reinterpret_cast<v2f*>(&raw[rawWr + srawof + 2]) = p1;
                    *reinterpret_cast<v2f*>(&raw[rawWr + srawof + 4]) = p2;
                    *reinterpret_cast<v2f*>(&raw[rawWr + srawof + 6]) = p3;
                    // ---- B: re-issue prefetch for step t+2 (mirror keeps
                    //      overrun addresses in-bounds; data unused) ----
                    const size_t on = (size_t)mirror(h0 - PAD + t + 2, HH)*(WW*DD) + sgoff;
                    ra  = *reinterpret_cast<const v4f*>(sp + on);
                    rb_ = *reinterpret_cast<const v4f*>(rp + on);

                    // ---- C: phase1(t): D-blur for d-pair -> planes ----
                    // point A: taps j=0..10 w[j]; point B: taps j=1..11 w[j-1]
                    v2f muA=(v2f)0.f, mmA=(v2f)0.f, muB=(v2f)0.f, mmB=(v2f)0.f;
                    float m12A=0.f, m12B=0.f;
                    if (!dedge) {
                        const float* r0 = &raw[rawRd + p_rbase];
#pragma unroll
                        for (int j = 0; j < 12; ++j) {
                            v2f sr = *reinterpret_cast<const v2f*>(r0 + 2*j);
                            if (j < 11) {
                                v2f p = pk_mul(sr, wpk[j]);
                                pk_add_acc(muA, p);
                                pk_fma_acc(mmA, p, sr);
                                m12A = fmaf(p.x, sr.y, m12A);
                            }
                            if (j > 0) {
                                v2f p = pk_mul(sr, wpk[j-1]);
                                pk_add_acc(muB, p);
                                pk_fma_acc(mmB, p, sr);
                                m12B = fmaf(p.x, sr.y, m12B);
                            }
                        }
                    } else {
                        const float* r0 = &raw[rawRd + p_wp*RS];
#pragma unroll
                        for (int j = 0; j < 12; ++j) {
                            v2f sr = *reinterpret_cast<const v2f*>(r0 + eoff[j]);
                            if (j < 11) {
                                v2f p = pk_mul(sr, wpk[j]);
                                pk_add_acc(muA, p);
                                pk_fma_acc(mmA, p, sr);
                                m12A = fmaf(p.x, sr.y, m12A);
                            }
                            if (j > 0) {
                                v2f p = pk_mul(sr, wpk[j-1]);
                                pk_add_acc(muB, p);
                                pk_fma_acc(mmB, p, sr);
                                m12B = fmaf(p.x, sr.y, m12B);
                            }
                        }
                    }
                    // plane writes: proven shapes (4x b64 + 2x b32)
                    *reinterpret_cast<v2f*>(&pl01[po01 + pA01])     = muA;
                    *reinterpret_cast<v2f*>(&pl01[po01 + pA01 + 2]) = muB;
                    *reinterpret_cast<v2f*>(&pl23[po01 + pA01])     = mmA;
                    *reinterpret_cast<v2f*>(&pl23[po01 + pA01 + 2]) = mmB;
                    pl4[po4 + pA4]     = m12A;
                    pl4[po4 + pA4 + 1] = m12B;
                }

                __syncthreads();                 // the ONLY barrier per step

                // ---- E: phase2(t): W-blur + H-ring + SSIM ----
                {
                    v2f v01 = (v2f)0.f, v23 = (v2f)0.f;
                    float v4v = 0.f;
                    const float* q01 = &pl01[po01 + wl*P01S + 2*dl2];
                    const float* q23 = &pl23[po01 + wl*P01S + 2*dl2];
                    const float* q4  = &pl4 [po4  + wl*P4S  + dl2];
#pragma unroll
                    for (int k = 0; k < KS; ++k) {
                        v2f w = wpk[k];
                        pk_fma_acc(v01, *reinterpret_cast<const v2f*>(q01 + k*P01S), w);
                        pk_fma_acc(v23, *reinterpret_cast<const v2f*>(q23 + k*P01S), w);
                        v4v = fmaf(w.x, q4[k*P4S], v4v);
                    }
#pragma unroll
                    for (int m = 0; m < 11; ++m) {
                        const int slot = (ts + m) % 11;   // static after unroll
                        v2f wt = wpk[10 - m];
                        pk_fma_acc(acc01[slot], v01, wt);
                        pk_fma_acc(acc23[slot], v23, wt);
                        acc4[slot]  = fmaf(wt.x, v4v, acc4[slot]);
                    }
                    if (t >= 10) {                        // emit h = h0 - 10 + t
                        float mu1 = acc01[ts].x, mu2 = acc01[ts].y;
                        float m11 = acc23[ts].x, m22 = acc23[ts].y, m12 = acc4[ts];
                        float mu1sq = mu1*mu1, mu2sq = mu2*mu2, mu12 = mu1*mu2;
                        float s1 = m11 - mu1sq, s2 = m22 - mu2sq, s12 = m12 - mu12;
                        const float C1 = 1e-4f, C2 = 9e-4f;
                        float num = (2.f*mu12 + C1) * (2.f*s12 + C2);
                        float den = (mu1sq + mu2sq + C1) * (s1 + s2 + C2) + 1e-12f;
                        float inv = __builtin_amdgcn_rcpf(den);
                        inv = inv * (2.0f - den * inv);   // 1 NR step -> ~1ulp
                        ssum = fmaf(num, inv, ssum);
                    }
                    acc01[ts] = (v2f)0.f; acc23[ts] = (v2f)0.f; acc4[ts] = 0.f;
                }

                rawRd ^= RAW_W; rawWr ^= RAW_W; po01 ^= P01_W; po4 ^= P4_W;
            }
        }
    }

    // ---- block reduction, one atomic per block ----
#pragma unroll
    for (int off = 32; off > 0; off >>= 1)
        ssum += __shfl_down(ssum, off, 64);
    __shared__ float lsum[4];
    int lane = tid & 63, wid = tid >> 6;
    if (lane == 0) lsum[wid] = ssum;
    __syncthreads();
    if (tid == 0)
        atomicAdd(out, -(lsum[0]+lsum[1]+lsum[2]+lsum[3]) * scale);
}

extern "C" void kernel_launch(void* const* d_in, const int* in_sizes, int n_in,
                              void* d_out, int out_size, void* d_ws, size_t ws_size,
                              hipStream_t stream) {
    const float* src = (const float*)d_in[0];
    const float* ref = (const float*)d_in[1];
    float* out = (float*)d_out;

    Wts wts;
    {
        double g[KS], s = 0.0;
        for (int i = 0; i < KS; ++i) {
            double a = (double)i - (KS - 1) / 2.0;
            g[i] = exp(-(a * a) / (2.0 * 1.5 * 1.5));
            s += g[i];
        }
        for (int i = 0; i < KS; ++i) wts.w[i] = (float)(g[i] / s);
    }

    const float scale = 1.0f / (float)NTOT;

    init_out<<<1, 64, 0, stream>>>(out);
    const int g = NBATCH * (HH/HT) * (WW/WT) * (DD/DT);   // 1000
    fused<<<g, 256, 0, stream>>>(src, ref, out, wts, scale);
}